// Round 14
// baseline (545.068 us; speedup 1.0000x reference)
//
#include <hip/hip_runtime.h>

#define SS 512
#define DD 768
#define TT 64

typedef __attribute__((ext_vector_type(2))) float f32x2;

__device__ __forceinline__ f32x2 vmax2(f32x2 a, f32x2 b) {
    return __builtin_elementwise_max(a, b);
}

// ---------------------------------------------------------------------------
// Kernel 1: FUSED emissions-GEMM + Viterbi forward scan.
// One block per batch, 320 threads = 5 waves:
//   waves 0-3 (producers): compute chunk c+1 of em (64 steps x 64 tags,
//     K=768) into em_lds[buf^1] AND global em, while
//   wave 4 (scan): runs the serial value-only recursion on chunk c from
//     em_lds[buf] (R10 structure: 16 bcast ds_read_b128 -> 32 pk_add ->
//     31 pk_max tree -> fmax -> +em -> ds_write; bit-exact vs reference).
// One __syncthreads per chunk boundary; producers use only intra-wave
// DS-FIFO ordering (no barriers) for their private Xs/Ws staging.
// em bit-identical to the old standalone gemm: each output accumulates
// k=0..767 sequentially with fmaf, bias added once at the end.
// waves_per_eu(1,2) -> 256-VGPR budget keeps scan's tpk[32] resident.
// ---------------------------------------------------------------------------
__global__ __launch_bounds__(320)
__attribute__((amdgpu_waves_per_eu(1, 2)))
void fused_gemm_viterbi(
    const float* __restrict__ X, const float* __restrict__ W,
    const float* __restrict__ bias, const float* __restrict__ trans,
    float* __restrict__ em, float* __restrict__ scoreHist,
    int* __restrict__ bestTag)
{
    __shared__ __align__(16) float em_lds[2][64][TT];   // 32 KB dbuf
    __shared__ __align__(16) float tr_lds[4096];        // 16 KB trans
    __shared__ __align__(16) float sc_lds[TT];          // 256 B score
    __shared__ __align__(16) float Xs[4][16][20];       // per-wave X stage
    __shared__ __align__(16) float Ws[4][16][64];       // per-wave W stage

    const int b    = blockIdx.x;
    const int tid  = threadIdx.x;
    const int wid  = tid >> 6;
    const int lane = tid & 63;

    float* emg = em + (size_t)b * SS * TT;
    float* sh  = scoreHist + (size_t)b * SS * TT;

    // ---- producer lambda: compute chunk ct (64 rows x 64 tags) ----
    // wave wid handles chunk-local rows [wid*16, wid*16+16).
    // lane -> (rgrp = lane>>4: 4 rows, cgrp = lane&15: 4 cols), 4x4 acc.
    const int rgrp = lane >> 4;
    const int cgrp = lane & 15;
    const int xrow = lane >> 2;   // staging: row 0..15
    const int xkq  = lane & 3;    // staging: k-quad
    float4 bv4;
    if (wid < 4) bv4 = *(const float4*)&bias[cgrp * 4];

    auto produce = [&](int ct, int nbuf) {
        const float4* X4 = (const float4*)X;
        const float4* W4 = (const float4*)W;
        const int rowbase = b * SS + ct * 64 + wid * 16;   // global row of stage-row 0

        float acc[4][4];
#pragma unroll
        for (int i = 0; i < 4; i++)
#pragma unroll
            for (int j = 0; j < 4; j++) acc[i][j] = 0.f;

        float4 xr = X4[(size_t)(rowbase + xrow) * 192 + xkq];
        float4 w0 = W4[(size_t)lane * 192 + 0];
        float4 w1 = W4[(size_t)lane * 192 + 1];
        float4 w2 = W4[(size_t)lane * 192 + 2];
        float4 w3 = W4[(size_t)lane * 192 + 3];

        for (int kt = 0; kt < 48; kt++) {
            // regs -> private LDS stage (intra-wave DS FIFO: no barrier)
            Xs[wid][xkq * 4 + 0][xrow] = xr.x;
            Xs[wid][xkq * 4 + 1][xrow] = xr.y;
            Xs[wid][xkq * 4 + 2][xrow] = xr.z;
            Xs[wid][xkq * 4 + 3][xrow] = xr.w;
            Ws[wid][ 0][lane] = w0.x;  Ws[wid][ 1][lane] = w0.y;
            Ws[wid][ 2][lane] = w0.z;  Ws[wid][ 3][lane] = w0.w;
            Ws[wid][ 4][lane] = w1.x;  Ws[wid][ 5][lane] = w1.y;
            Ws[wid][ 6][lane] = w1.z;  Ws[wid][ 7][lane] = w1.w;
            Ws[wid][ 8][lane] = w2.x;  Ws[wid][ 9][lane] = w2.y;
            Ws[wid][10][lane] = w2.z;  Ws[wid][11][lane] = w2.w;
            Ws[wid][12][lane] = w3.x;  Ws[wid][13][lane] = w3.y;
            Ws[wid][14][lane] = w3.z;  Ws[wid][15][lane] = w3.w;

            if (kt < 47) {  // prefetch next k-tile
                xr = X4[(size_t)(rowbase + xrow) * 192 + (kt + 1) * 4 + xkq];
                w0 = W4[(size_t)lane * 192 + (kt + 1) * 4 + 0];
                w1 = W4[(size_t)lane * 192 + (kt + 1) * 4 + 1];
                w2 = W4[(size_t)lane * 192 + (kt + 1) * 4 + 2];
                w3 = W4[(size_t)lane * 192 + (kt + 1) * 4 + 3];
            }

#pragma unroll
            for (int k = 0; k < 16; k++) {
                float a[4], bvv[4];
                *(float4*)&a[0]   = *(const float4*)&Xs[wid][k][rgrp * 4];
                *(float4*)&bvv[0] = *(const float4*)&Ws[wid][k][cgrp * 4];
#pragma unroll
                for (int i = 0; i < 4; i++)
#pragma unroll
                    for (int j = 0; j < 4; j++)
                        acc[i][j] = fmaf(a[i], bvv[j], acc[i][j]);
            }
        }

        // epilogue: +bias, write LDS dbuf + global em
#pragma unroll
        for (int i = 0; i < 4; i++) {
            const int rl = wid * 16 + rgrp * 4 + i;   // chunk-local row
            float4 o;
            o.x = acc[i][0] + bv4.x;  o.y = acc[i][1] + bv4.y;
            o.z = acc[i][2] + bv4.z;  o.w = acc[i][3] + bv4.w;
            *(float4*)&em_lds[nbuf][rl][cgrp * 4] = o;
            *(float4*)&emg[(size_t)(ct * 64 + rl) * TT + cgrp * 4] = o;
        }
    };

    // ---- prologue ----
    f32x2 tpk[32];
    if (wid == 4) {
        // stage trans (intra-wave), load packed column
        float4* dst = (float4*)tr_lds;
        const float4* src = (const float4*)trans;
#pragma unroll
        for (int i = 0; i < 16; i++) dst[lane + i * 64] = src[lane + i * 64];
#pragma unroll
        for (int j = 0; j < 32; j++) {
            tpk[j].x = tr_lds[(2 * j) * TT + lane];
            tpk[j].y = tr_lds[(2 * j + 1) * TT + lane];
        }
    } else {
        produce(0, 0);
    }
    __syncthreads();

    // scan init (s = 0)
    float sc = 0.f;
    float4 sq[16];
    if (wid == 4) {
        sc = em_lds[0][0][lane];
        sc_lds[lane] = sc;
        sh[lane] = sc;
        const float4* sb = (const float4*)sc_lds;
#pragma unroll
        for (int i = 0; i < 16; i++) sq[i] = sb[i];
    }

    // ---- steady state: scan chunk cn || produce chunk cn+1 ----
    int buf = 0;
    for (int cn = 0; cn < 8; cn++) {
        if (wid == 4) {
            const int s0 = cn * 64;
            const int sb_ = (cn == 0) ? 1 : s0;
#pragma unroll 4
            for (int s = sb_; s < s0 + 64; s++) {
                const float em_v = em_lds[buf][s - s0][lane];
                const f32x2* sq2 = (const f32x2*)sq;
                f32x2 pk[32];
#pragma unroll
                for (int j = 0; j < 32; j++) pk[j] = sq2[j] + tpk[j];
#pragma unroll
                for (int m = 16; m >= 1; m >>= 1)
#pragma unroll
                    for (int j = 0; j < 16; j++) {
                        if (j < m) pk[j] = vmax2(pk[j], pk[j + m]);
                    }
                sc = fmaxf(pk[0].x, pk[0].y) + em_v;

                sc_lds[lane] = sc;
                {
                    const float4* sb = (const float4*)sc_lds;
#pragma unroll
                    for (int i = 0; i < 16; i++) sq[i] = sb[i];
                }
                sh[(size_t)s * TT + lane] = sc;
            }
        } else if (cn < 7) {
            produce(cn + 1, buf ^ 1);
        }
        __syncthreads();
        buf ^= 1;
    }

    // final argmax across lanes (first-index ties)
    if (wid == 4) {
        float fv = sc;
        int   fa = lane;
#pragma unroll
        for (int m = 1; m <= 32; m <<= 1) {
            const float vo = __shfl_xor(fv, m, 64);
            const int   ao = __shfl_xor(fa, m, 64);
            if (vo > fv || (vo == fv && ao < fa)) { fv = vo; fa = ao; }
        }
        if (lane == 0) bestTag[b] = fa;
    }
}

// ---------------------------------------------------------------------------
// Kernel 2: backpointer recompute (R13-validated). One wave per (b,s),
// lane = cur. Max value known bit-exact from scoreHist; first index with
// fl(fl(score+trans)+em) == sh  == numpy first-index argmax.
// ---------------------------------------------------------------------------
__global__ __launch_bounds__(256) void bp_kernel(
    const float* __restrict__ scoreHist, const float* __restrict__ em,
    const float* __restrict__ trans, unsigned char* __restrict__ hist8)
{
    __shared__ __align__(16) float tr_lds[4096];
    const int tid = threadIdx.x;
    {
        const float4* src = (const float4*)trans;
        float4* dst = (float4*)tr_lds;
        for (int i = tid; i < 1024; i += 256) dst[i] = src[i];
    }
    __syncthreads();

    const int wv   = tid >> 6;
    const int lane = tid & 63;
    const int g    = blockIdx.x * 4 + wv;
    const int b    = g / 511;
    const int s    = 1 + (g % 511);

    const f32x2* sb2 = (const f32x2*)(scoreHist + ((size_t)b * SS + (s - 1)) * TT);
    const float em_v = em[((size_t)b * SS + s) * TT + lane];
    const float sh_v = scoreHist[((size_t)b * SS + s) * TT + lane];

    f32x2 tpk[32];
#pragma unroll
    for (int j = 0; j < 32; j++) {
        tpk[j].x = tr_lds[(2 * j) * TT + lane];
        tpk[j].y = tr_lds[(2 * j + 1) * TT + lane];
    }

    f32x2 em2; em2.x = em_v; em2.y = em_v;
    f32x2 v2[32];
#pragma unroll
    for (int j = 0; j < 32; j++) {
        f32x2 cand = sb2[j] + tpk[j];
        v2[j] = cand + em2;
    }

    int idx = 63;
#pragma unroll
    for (int j = 31; j >= 0; j--) {
        idx = (v2[j].y == sh_v) ? 2 * j + 1 : idx;
        idx = (v2[j].x == sh_v) ? 2 * j     : idx;
    }

    hist8[((size_t)b * SS + s) * TT + lane] = (unsigned char)idx;
}

// ---------------------------------------------------------------------------
// Kernel 3: backtrack via readlane pointer-chase (R13-validated).
// ---------------------------------------------------------------------------
__global__ __launch_bounds__(64) void backtrack(
    const unsigned char* __restrict__ hist8, const int* __restrict__ bestTag,
    int* __restrict__ out)
{
    __shared__ int tags[SS];

    const int b    = blockIdx.x;
    const int lane = threadIdx.x;
    const unsigned char* h8 = hist8 + (size_t)b * SS * TT;

    int tag = bestTag[b];
    if (lane == 0) tags[511] = tag;

    int r0 = h8[511 * TT + lane];
    int r1 = h8[510 * TT + lane];
    int r2 = h8[509 * TT + lane];
    int r3 = h8[508 * TT + lane];

    for (int sb = 511; sb >= 11; sb -= 4) {
        tag = __builtin_amdgcn_readlane(r0, tag);
        if (lane == 0) tags[sb - 1] = tag;
        r0 = h8[(sb - 4) * TT + lane];
        tag = __builtin_amdgcn_readlane(r1, tag);
        if (lane == 0) tags[sb - 2] = tag;
        r1 = h8[(sb - 5) * TT + lane];
        tag = __builtin_amdgcn_readlane(r2, tag);
        if (lane == 0) tags[sb - 3] = tag;
        r2 = h8[(sb - 6) * TT + lane];
        tag = __builtin_amdgcn_readlane(r3, tag);
        if (lane == 0) tags[sb - 4] = tag;
        r3 = h8[(sb - 7) * TT + lane];
    }
    tag = __builtin_amdgcn_readlane(r0, tag);  if (lane == 0) tags[6] = tag;
    tag = __builtin_amdgcn_readlane(r1, tag);  if (lane == 0) tags[5] = tag;
    tag = __builtin_amdgcn_readlane(r2, tag);  if (lane == 0) tags[4] = tag;
    tag = __builtin_amdgcn_readlane(r3, tag);  if (lane == 0) tags[3] = tag;
    int q0 = h8[3 * TT + lane];
    int q1 = h8[2 * TT + lane];
    int q2 = h8[1 * TT + lane];
    tag = __builtin_amdgcn_readlane(q0, tag);  if (lane == 0) tags[2] = tag;
    tag = __builtin_amdgcn_readlane(q1, tag);  if (lane == 0) tags[1] = tag;
    tag = __builtin_amdgcn_readlane(q2, tag);  if (lane == 0) tags[0] = tag;

    __syncthreads();
#pragma unroll
    for (int s = 0; s < 8; s++)
        out[(size_t)b * SS + s * 64 + lane] = tags[s * 64 + lane];
}

// ---------------------------------------------------------------------------
extern "C" void kernel_launch(void* const* d_in, const int* in_sizes, int n_in,
                              void* d_out, int out_size, void* d_ws, size_t ws_size,
                              hipStream_t stream)
{
    const float* X     = (const float*)d_in[0];  // [64,512,768]
    const float* W     = (const float*)d_in[1];  // [64,768]
    const float* bias  = (const float*)d_in[2];  // [64]
    const float* trans = (const float*)d_in[3];  // [64,64]
    int* out = (int*)d_out;                      // [64,512] int32

    char* ws = (char*)d_ws;
    float*         em        = (float*)ws;                      // 8,388,608 B
    float*         scoreHist = (float*)(ws + 8388608);          // 8,388,608 B
    unsigned char* hist8     = (unsigned char*)(ws + 16777216); // 2,097,152 B
    int*           bestTag   = (int*)(ws + 18874368);           // 256 B

    fused_gemm_viterbi<<<dim3(64), dim3(320), 0, stream>>>(
        X, W, bias, trans, em, scoreHist, bestTag);
    bp_kernel<<<dim3(8176), dim3(256), 0, stream>>>(scoreHist, em, trans, hist8);
    backtrack<<<dim3(64), dim3(64), 0, stream>>>(hist8, bestTag, out);
}

// Round 15
// 240.097 us; speedup vs baseline: 2.2702x; 2.2702x over previous
//
#include <hip/hip_runtime.h>

#define SS 512
#define DD 768
#define TT 64

typedef __attribute__((ext_vector_type(2))) float f32x2;

__device__ __forceinline__ f32x2 vmax2(f32x2 a, f32x2 b) {
    return __builtin_elementwise_max(a, b);
}

// ---------------------------------------------------------------------------
// Kernel 1: emissions GEMM  em[b*512+s][t] = sum_d x[b,s,d]*W[t,d] + bias[t]
// 128x64 tile, grid 256, 256 threads, thread tile 8x4 (R1-validated).
// Better FMA:ds_read ratio (10.7:1) than the 64-tile config (8:1) -- the
// gemm is DS-throughput-bound, so this is the lever.
// ---------------------------------------------------------------------------
__global__ __launch_bounds__(256) void emis_gemm(
    const float* __restrict__ X, const float* __restrict__ W,
    const float* __restrict__ bias, float* __restrict__ em)
{
    __shared__ __align__(16) float Xs[16][132];
    __shared__ __align__(16) float Ws[16][68];

    const int tid = threadIdx.x;
    const int m0  = blockIdx.x * 128;
    const int tm  = tid >> 4;
    const int tn  = tid & 15;
    const int lm  = tid >> 2;
    const int lkq = tid & 3;
    const int wt  = tid & 63;
    const int wkq = tid >> 6;

    float acc[8][4];
#pragma unroll
    for (int i = 0; i < 8; i++)
#pragma unroll
        for (int j = 0; j < 4; j++) acc[i][j] = 0.f;

    float4 xr0, xr1, wr;
    xr0 = *(const float4*)&X[(size_t)(m0 + lm) * DD + lkq * 4];
    xr1 = *(const float4*)&X[(size_t)(m0 + lm + 64) * DD + lkq * 4];
    wr  = *(const float4*)&W[(size_t)wt * DD + wkq * 4];

    for (int t = 0; t < 48; t++) {
        Xs[lkq * 4 + 0][lm] = xr0.x;  Xs[lkq * 4 + 1][lm] = xr0.y;
        Xs[lkq * 4 + 2][lm] = xr0.z;  Xs[lkq * 4 + 3][lm] = xr0.w;
        Xs[lkq * 4 + 0][lm + 64] = xr1.x;  Xs[lkq * 4 + 1][lm + 64] = xr1.y;
        Xs[lkq * 4 + 2][lm + 64] = xr1.z;  Xs[lkq * 4 + 3][lm + 64] = xr1.w;
        Ws[wkq * 4 + 0][wt] = wr.x;  Ws[wkq * 4 + 1][wt] = wr.y;
        Ws[wkq * 4 + 2][wt] = wr.z;  Ws[wkq * 4 + 3][wt] = wr.w;
        __syncthreads();

        if (t < 47) {
            const int k0 = (t + 1) * 16;
            xr0 = *(const float4*)&X[(size_t)(m0 + lm) * DD + k0 + lkq * 4];
            xr1 = *(const float4*)&X[(size_t)(m0 + lm + 64) * DD + k0 + lkq * 4];
            wr  = *(const float4*)&W[(size_t)wt * DD + k0 + wkq * 4];
        }

#pragma unroll
        for (int k = 0; k < 16; k++) {
            float a[8], bv[4];
            *(float4*)&a[0] = *(const float4*)&Xs[k][tm * 8];
            *(float4*)&a[4] = *(const float4*)&Xs[k][tm * 8 + 4];
            *(float4*)&bv[0] = *(const float4*)&Ws[k][tn * 4];
#pragma unroll
            for (int i = 0; i < 8; i++)
#pragma unroll
                for (int j = 0; j < 4; j++)
                    acc[i][j] = fmaf(a[i], bv[j], acc[i][j]);
        }
        __syncthreads();
    }

    const float4 bv4 = *(const float4*)&bias[tn * 4];
#pragma unroll
    for (int i = 0; i < 8; i++) {
        const size_t row = (size_t)(m0 + tm * 8 + i);
        float4 o;
        o.x = acc[i][0] + bv4.x;  o.y = acc[i][1] + bv4.y;
        o.z = acc[i][2] + bv4.z;  o.w = acc[i][3] + bv4.w;
        *(float4*)&em[row * TT + tn * 4] = o;
    }
}

// ---------------------------------------------------------------------------
// Kernel 2: Viterbi forward, VALUE ONLY (R10 code, 112 us measured).
// One wave per batch, waves_per_eu(1,1) keeps tpk[32] VGPR-resident.
// Step: 16 broadcast ds_read_b128 -> 32 pk_add -> 31 pk_max tree -> fmax
// -> +em -> ds_write. Bit-exact vs reference (monotone rounding).
// ---------------------------------------------------------------------------
__global__ __launch_bounds__(64)
__attribute__((amdgpu_waves_per_eu(1, 1)))
void viterbi_fwd(
    const float* __restrict__ em, const float* __restrict__ trans,
    float* __restrict__ scoreHist, int* __restrict__ bestTag)
{
    __shared__ __align__(16) float sc_lds[TT];
    __shared__ __align__(16) float tr_lds[4096];

    const int b    = blockIdx.x;
    const int lane = threadIdx.x;
    const float* emb = em + (size_t)b * SS * TT;
    float* sh = scoreHist + (size_t)b * SS * TT;

    {
        float4* dst = (float4*)tr_lds;
        const float4* src = (const float4*)trans;
#pragma unroll
        for (int i = 0; i < 16; i++) dst[lane + i * 64] = src[lane + i * 64];
    }
    __syncthreads();

    // tpk[j] = (trans[2j][lane], trans[2j+1][lane])
    f32x2 tpk[32];
#pragma unroll
    for (int j = 0; j < 32; j++) {
        tpk[j].x = tr_lds[(2 * j) * TT + lane];
        tpk[j].y = tr_lds[(2 * j + 1) * TT + lane];
    }

    const float em0 = emb[lane];
    sc_lds[lane] = em0;
    sh[lane] = em0;   // score_0
    float sc = em0;

    float er0 = emb[1 * TT + lane];
    float er1 = emb[2 * TT + lane];
    float er2 = emb[3 * TT + lane];
    float er3 = emb[4 * TT + lane];

    float4 sq[16];
    {
        const float4* sb = (const float4*)sc_lds;
#pragma unroll
        for (int i = 0; i < 16; i++) sq[i] = sb[i];
    }

    auto step = [&](int s, float em_v) {
        const f32x2* sq2 = (const f32x2*)sq;
        f32x2 pk[32];
#pragma unroll
        for (int j = 0; j < 32; j++) pk[j] = sq2[j] + tpk[j];

#pragma unroll
        for (int m = 16; m >= 1; m >>= 1)
#pragma unroll
            for (int j = 0; j < 16; j++) {
                if (j < m) pk[j] = vmax2(pk[j], pk[j + m]);
            }
        sc = fmaxf(pk[0].x, pk[0].y) + em_v;

        sc_lds[lane] = sc;
        {
            const float4* sb = (const float4*)sc_lds;
#pragma unroll
            for (int i = 0; i < 16; i++) sq[i] = sb[i];
        }
        sh[s * TT + lane] = sc;
    };

    for (int sb = 1; sb <= 505; sb += 4) {
        step(sb + 0, er0);  er0 = emb[(sb + 4) * TT + lane];
        step(sb + 1, er1);  er1 = emb[(sb + 5) * TT + lane];
        step(sb + 2, er2);  er2 = emb[(sb + 6) * TT + lane];
        step(sb + 3, er3);  er3 = emb[((sb + 7) <= 511 ? (sb + 7) : 511) * TT + lane];
    }
    step(509, er0);
    step(510, er1);
    step(511, er2);

    float fv = sc;
    int   fa = lane;
#pragma unroll
    for (int m = 1; m <= 32; m <<= 1) {
        const float vo = __shfl_xor(fv, m, 64);
        const int   ao = __shfl_xor(fa, m, 64);
        if (vo > fv || (vo == fv && ao < fa)) { fv = vo; fa = ao; }
    }
    if (lane == 0) bestTag[b] = fa;
}

// ---------------------------------------------------------------------------
// Kernel 3: backpointer recompute (R13-validated). One wave per (b,s),
// lane = cur. Max value known bit-exact from scoreHist; first index with
// fl(fl(score+trans)+em) == sh  == numpy first-index argmax.
// ---------------------------------------------------------------------------
__global__ __launch_bounds__(256) void bp_kernel(
    const float* __restrict__ scoreHist, const float* __restrict__ em,
    const float* __restrict__ trans, unsigned char* __restrict__ hist8)
{
    __shared__ __align__(16) float tr_lds[4096];
    const int tid = threadIdx.x;
    {
        const float4* src = (const float4*)trans;
        float4* dst = (float4*)tr_lds;
        for (int i = tid; i < 1024; i += 256) dst[i] = src[i];
    }
    __syncthreads();

    const int wv   = tid >> 6;
    const int lane = tid & 63;
    const int g    = blockIdx.x * 4 + wv;
    const int b    = g / 511;
    const int s    = 1 + (g % 511);

    const f32x2* sb2 = (const f32x2*)(scoreHist + ((size_t)b * SS + (s - 1)) * TT);
    const float em_v = em[((size_t)b * SS + s) * TT + lane];
    const float sh_v = scoreHist[((size_t)b * SS + s) * TT + lane];

    f32x2 tpk[32];
#pragma unroll
    for (int j = 0; j < 32; j++) {
        tpk[j].x = tr_lds[(2 * j) * TT + lane];
        tpk[j].y = tr_lds[(2 * j + 1) * TT + lane];
    }

    f32x2 em2; em2.x = em_v; em2.y = em_v;
    f32x2 v2[32];
#pragma unroll
    for (int j = 0; j < 32; j++) {
        f32x2 cand = sb2[j] + tpk[j];
        v2[j] = cand + em2;
    }

    int idx = 63;
#pragma unroll
    for (int j = 31; j >= 0; j--) {
        idx = (v2[j].y == sh_v) ? 2 * j + 1 : idx;
        idx = (v2[j].x == sh_v) ? 2 * j     : idx;
    }

    hist8[((size_t)b * SS + s) * TT + lane] = (unsigned char)idx;
}

// ---------------------------------------------------------------------------
// Kernel 4: backtrack via readlane pointer-chase (R13-validated).
// ---------------------------------------------------------------------------
__global__ __launch_bounds__(64) void backtrack(
    const unsigned char* __restrict__ hist8, const int* __restrict__ bestTag,
    int* __restrict__ out)
{
    __shared__ int tags[SS];

    const int b    = blockIdx.x;
    const int lane = threadIdx.x;
    const unsigned char* h8 = hist8 + (size_t)b * SS * TT;

    int tag = bestTag[b];
    if (lane == 0) tags[511] = tag;

    int r0 = h8[511 * TT + lane];
    int r1 = h8[510 * TT + lane];
    int r2 = h8[509 * TT + lane];
    int r3 = h8[508 * TT + lane];

    for (int sb = 511; sb >= 11; sb -= 4) {
        tag = __builtin_amdgcn_readlane(r0, tag);
        if (lane == 0) tags[sb - 1] = tag;
        r0 = h8[(sb - 4) * TT + lane];
        tag = __builtin_amdgcn_readlane(r1, tag);
        if (lane == 0) tags[sb - 2] = tag;
        r1 = h8[(sb - 5) * TT + lane];
        tag = __builtin_amdgcn_readlane(r2, tag);
        if (lane == 0) tags[sb - 3] = tag;
        r2 = h8[(sb - 6) * TT + lane];
        tag = __builtin_amdgcn_readlane(r3, tag);
        if (lane == 0) tags[sb - 4] = tag;
        r3 = h8[(sb - 7) * TT + lane];
    }
    tag = __builtin_amdgcn_readlane(r0, tag);  if (lane == 0) tags[6] = tag;
    tag = __builtin_amdgcn_readlane(r1, tag);  if (lane == 0) tags[5] = tag;
    tag = __builtin_amdgcn_readlane(r2, tag);  if (lane == 0) tags[4] = tag;
    tag = __builtin_amdgcn_readlane(r3, tag);  if (lane == 0) tags[3] = tag;
    int q0 = h8[3 * TT + lane];
    int q1 = h8[2 * TT + lane];
    int q2 = h8[1 * TT + lane];
    tag = __builtin_amdgcn_readlane(q0, tag);  if (lane == 0) tags[2] = tag;
    tag = __builtin_amdgcn_readlane(q1, tag);  if (lane == 0) tags[1] = tag;
    tag = __builtin_amdgcn_readlane(q2, tag);  if (lane == 0) tags[0] = tag;

    __syncthreads();
#pragma unroll
    for (int s = 0; s < 8; s++)
        out[(size_t)b * SS + s * 64 + lane] = tags[s * 64 + lane];
}

// ---------------------------------------------------------------------------
extern "C" void kernel_launch(void* const* d_in, const int* in_sizes, int n_in,
                              void* d_out, int out_size, void* d_ws, size_t ws_size,
                              hipStream_t stream)
{
    const float* X     = (const float*)d_in[0];  // [64,512,768]
    const float* W     = (const float*)d_in[1];  // [64,768]
    const float* bias  = (const float*)d_in[2];  // [64]
    const float* trans = (const float*)d_in[3];  // [64,64]
    int* out = (int*)d_out;                      // [64,512] int32

    char* ws = (char*)d_ws;
    float*         em        = (float*)ws;                      // 8,388,608 B
    float*         scoreHist = (float*)(ws + 8388608);          // 8,388,608 B
    unsigned char* hist8     = (unsigned char*)(ws + 16777216); // 2,097,152 B
    int*           bestTag   = (int*)(ws + 18874368);           // 256 B

    emis_gemm<<<dim3(256), dim3(256), 0, stream>>>(X, W, bias, em);
    viterbi_fwd<<<dim3(64), dim3(64), 0, stream>>>(em, trans, scoreHist, bestTag);
    bp_kernel<<<dim3(8176), dim3(256), 0, stream>>>(scoreHist, em, trans, hist8);
    backtrack<<<dim3(64), dim3(64), 0, stream>>>(hist8, bestTag, out);
}